// Round 3
// baseline (848.490 us; speedup 1.0000x reference)
//
#include <hip/hip_runtime.h>
#include <math.h>

#define Bq 4
#define Nn 4
#define Cc 256
#define Hh 100
#define Ww 152
#define HW (Hh * Ww)       // 15200
#define NP4 (HW / 4)       // 3800 float4-groups per image
#define WG4 (Ww / 4)       // 38 float4-groups per row
#define NMAP (Bq * 5)      // 20
#define SSPLIT 2
#define SCH (Cc / SSPLIT)  // 128 channels per sums-split
#define CSPLIT 16
#define CCH (Cc / CSPLIT)  // 16 channels per census-split (count <= 144 fits u8)
#define TILE 32
#define TPB (HW / TILE)    // 475
#define LSTR 40            // LDS row stride (floats), 160 B (16B-aligned)

// ws layout (bytes):
//   thr  : float [NMAP*HW]        @ 0          (1,216,000)   live: k_thr -> k_census
//   wt   : float [Bq*Nn*HW]       @ 1,216,000  (  972,800)   live: k_soft -> k_fuse
//   wT   : float [Cc*Cc]          @ 2,188,800  (  262,144)   live: k_wtr  -> k_fuse
//   SHR  :                        @ 2,450,944
//     as ps   : double[2*NMAP*HW] (4,864,000)  live: k_sums -> k_thr
//     as pcnt : u32[16*Bq*HW]     (3,891,200)  live: k_census -> k_soft  (reuse: ps dead)
// total 7,314,944 B  (< 8.77 MB proven available in round 2)
#define OFF_THR 0
#define OFF_WT  1216000
#define OFF_WTR 2188800
#define OFF_SHR 2450944

// ---------------------------------------------------------------------------
// K0: transpose w_fuse [o][c] -> wT [c][o]
// ---------------------------------------------------------------------------
__global__ __launch_bounds__(256) void k_wtr(const float* __restrict__ wf,
                                             float* __restrict__ wT) {
    int t = blockIdx.x * blockDim.x + threadIdx.x;
    if (t >= Cc * Cc) return;
    int c = t / Cc, o = t % Cc;
    wT[c * Cc + o] = wf[o * Cc + c];
}

// ---------------------------------------------------------------------------
// K1: fp64 partial channel sums, 2-way channel split, float4 loads.
// thread <-> (map m, float4-group p4); blockIdx.y = split.
// ---------------------------------------------------------------------------
__global__ __launch_bounds__(256) void k_sums(const float* __restrict__ feat,
                                              const float* __restrict__ nearf,
                                              double* __restrict__ ps) {
    int id = blockIdx.x * 256 + threadIdx.x;
    if (id >= NMAP * NP4) return;
    int s = blockIdx.y;
    int m = id / NP4, p4 = id % NP4;
    int b = m / 5, r = m % 5;
    const float* src = (r == 0)
        ? (feat + (size_t)b * Cc * HW)
        : (nearf + ((size_t)(b * Nn + (r - 1))) * Cc * HW);
    src += (size_t)(s * SCH) * HW + (size_t)p4 * 4;
    double a0 = 0, a1 = 0, a2 = 0, a3 = 0;
#pragma unroll 8
    for (int c = 0; c < SCH; ++c) {
        float4 v = *(const float4*)(src + (size_t)c * HW);
        a0 += (double)v.x; a1 += (double)v.y; a2 += (double)v.z; a3 += (double)v.w;
    }
    double* dst = ps + ((size_t)s * NMAP + m) * HW + (size_t)p4 * 4;
    dst[0] = a0; dst[1] = a1; dst[2] = a2; dst[3] = a3;
}

// ---------------------------------------------------------------------------
// K2: box-9 over (ps0+ps1) -> fp64 avg -> exact float threshold.
// thr = smallest float >= avg  =>  fp32 (v >= thr) == fp64 ((double)v >= avg).
// ---------------------------------------------------------------------------
__global__ __launch_bounds__(256) void k_thr(const double* __restrict__ ps,
                                             float* __restrict__ thr) {
    int t = blockIdx.x * 256 + threadIdx.x;
    if (t >= NMAP * HW) return;
    int m = t / HW, p = t % HW;
    int i = p / Ww, j = p % Ww;
    int im = (i > 0) ? i - 1 : 0;
    int ip = (i < Hh - 1) ? i + 1 : Hh - 1;
    int jm = (j > 0) ? j - 1 : 0;
    int jp = (j < Ww - 1) ? j + 1 : Ww - 1;
    int off[9];
    off[0] = im * Ww + jm; off[1] = im * Ww + j; off[2] = im * Ww + jp;
    off[3] = i  * Ww + jm; off[4] = i  * Ww + j; off[5] = i  * Ww + jp;
    off[6] = ip * Ww + jm; off[7] = ip * Ww + j; off[8] = ip * Ww + jp;
    const double* s0 = ps + (size_t)m * HW;
    const double* s1 = ps + ((size_t)NMAP + m) * HW;
    double a = 0.0;
#pragma unroll
    for (int k = 0; k < 9; ++k) a += s0[off[k]] + s1[off[k]];
    a *= (1.0 / (9.0 * (double)Cc));
    float f = (float)a;
    if ((double)f < a) f = nextafterf(f, HUGE_VALF);
    thr[t] = f;
}

// ---------------------------------------------------------------------------
// K3: census. thread <-> (b, row i, float4-group g) = 4 pixels.
// Per map-row: 1 aligned float4 + 2 clamped dwords -> 6 stencil columns.
// Column clamp is free: at g==0, max(j0-1,0) loads m.x (the replicate value);
// at g==37, min(j0+4,151) loads m.w. CSPLIT=16 -> counts <= 144, packed 4xu8.
// ---------------------------------------------------------------------------
__global__ __launch_bounds__(256) void k_census(const float* __restrict__ feat,
                                                const float* __restrict__ nearf,
                                                const float* __restrict__ thr,
                                                unsigned* __restrict__ pcnt) {
    int id = blockIdx.x * 256 + threadIdx.x;
    if (id >= Bq * NP4) return;
    int sp = blockIdx.y;
    int b = id / NP4, p4 = id % NP4;
    int i = p4 / WG4, g = p4 % WG4;
    int j0 = g * 4;
    int im = (i > 0) ? i - 1 : 0;
    int ip = (i < Hh - 1) ? i + 1 : Hh - 1;
    int jl = (j0 > 0) ? j0 - 1 : 0;
    int jr = (j0 + 4 < Ww) ? j0 + 4 : Ww - 1;
    int offm[3], offl[3], offr[3];
    {
        int ro[3] = { im * Ww, i * Ww, ip * Ww };
#pragma unroll
        for (int r = 0; r < 3; ++r) {
            offm[r] = ro[r] + j0; offl[r] = ro[r] + jl; offr[r] = ro[r] + jr;
        }
    }
    int p0 = i * Ww + j0;

    const float* tb = thr + (size_t)b * 5 * HW;
    float tf[4], tn[4][4];
#pragma unroll
    for (int k = 0; k < 4; ++k) tf[k] = tb[p0 + k];
#pragma unroll
    for (int n = 0; n < 4; ++n)
#pragma unroll
        for (int k = 0; k < 4; ++k) tn[n][k] = tb[(size_t)(n + 1) * HW + p0 + k];

    const float* fb = feat + ((size_t)b * Cc + sp * CCH) * HW;
    const float* nb = nearf + ((size_t)(b * Nn) * Cc + sp * CCH) * HW;

    int cnt[4][4];  // [n][k]
#pragma unroll
    for (int n = 0; n < 4; ++n)
#pragma unroll
        for (int k = 0; k < 4; ++k) cnt[n][k] = 0;

    for (int c = 0; c < CCH; ++c) {
        float v[3][6];
        const float* fc = fb + (size_t)c * HW;
#pragma unroll
        for (int r = 0; r < 3; ++r) {
            float4 m4 = *(const float4*)(fc + offm[r]);
            v[r][0] = fc[offl[r]];
            v[r][1] = m4.x; v[r][2] = m4.y; v[r][3] = m4.z; v[r][4] = m4.w;
            v[r][5] = fc[offr[r]];
        }
        unsigned fm[4];
#pragma unroll
        for (int k = 0; k < 4; ++k) {
            unsigned msk = 0;
#pragma unroll
            for (int r = 0; r < 3; ++r)
#pragma unroll
                for (int d = 0; d < 3; ++d)
                    msk |= (unsigned)(v[r][k + d] >= tf[k]) << (r * 3 + d);
            fm[k] = msk;
        }
#pragma unroll
        for (int n = 0; n < 4; ++n) {
            const float* nc = nb + ((size_t)n * Cc + c) * HW;
#pragma unroll
            for (int r = 0; r < 3; ++r) {
                float4 m4 = *(const float4*)(nc + offm[r]);
                v[r][0] = nc[offl[r]];
                v[r][1] = m4.x; v[r][2] = m4.y; v[r][3] = m4.z; v[r][4] = m4.w;
                v[r][5] = nc[offr[r]];
            }
#pragma unroll
            for (int k = 0; k < 4; ++k) {
                unsigned msk = 0;
#pragma unroll
                for (int r = 0; r < 3; ++r)
#pragma unroll
                    for (int d = 0; d < 3; ++d)
                        msk |= (unsigned)(v[r][k + d] >= tn[n][k]) << (r * 3 + d);
                cnt[n][k] += 9 - __popc(fm[k] ^ msk);
            }
        }
    }
    uint4 outv;
    outv.x = (unsigned)cnt[0][0] | ((unsigned)cnt[1][0] << 8) | ((unsigned)cnt[2][0] << 16) | ((unsigned)cnt[3][0] << 24);
    outv.y = (unsigned)cnt[0][1] | ((unsigned)cnt[1][1] << 8) | ((unsigned)cnt[2][1] << 16) | ((unsigned)cnt[3][1] << 24);
    outv.z = (unsigned)cnt[0][2] | ((unsigned)cnt[1][2] << 8) | ((unsigned)cnt[2][2] << 16) | ((unsigned)cnt[3][2] << 24);
    outv.w = (unsigned)cnt[0][3] | ((unsigned)cnt[1][3] << 8) | ((unsigned)cnt[2][3] << 16) | ((unsigned)cnt[3][3] << 24);
    *(uint4*)(pcnt + (size_t)sp * (Bq * HW) + (size_t)b * HW + p0) = outv;
}

// ---------------------------------------------------------------------------
// K4: SWAR-reduce 16 packed u8x4 partials -> softmax over N -> wt[b][n][p]
// per-16-bit lane max = 16*144 = 2304 (no overflow).
// ---------------------------------------------------------------------------
__global__ __launch_bounds__(256) void k_soft(const unsigned* __restrict__ pcnt,
                                              float* __restrict__ wt) {
    int t = blockIdx.x * 256 + threadIdx.x;
    if (t >= Bq * HW) return;
    unsigned acc02 = 0, acc13 = 0;
#pragma unroll
    for (int s = 0; s < CSPLIT; ++s) {
        unsigned v = pcnt[(size_t)s * (Bq * HW) + t];
        acc02 += v & 0x00FF00FFu;
        acc13 += (v >> 8) & 0x00FF00FFu;
    }
    float c0 = (float)(acc02 & 0xFFFF);
    float c2 = (float)(acc02 >> 16);
    float c1 = (float)(acc13 & 0xFFFF);
    float c3 = (float)(acc13 >> 16);
    float mx = fmaxf(fmaxf(c0, c1), fmaxf(c2, c3));
    float e0 = expf(c0 - mx), e1 = expf(c1 - mx), e2 = expf(c2 - mx), e3 = expf(c3 - mx);
    float rs = 1.0f / (e0 + e1 + e2 + e3);
    int b = t / HW, p = t % HW;
    float* wb = wt + (size_t)b * Nn * HW + p;
    wb[0 * (size_t)HW] = e0 * rs;
    wb[1 * (size_t)HW] = e1 * rs;
    wb[2 * (size_t)HW] = e2 * rs;
    wb[3 * (size_t)HW] = e3 * rs;
}

// ---------------------------------------------------------------------------
// K5: fused = feat + sum_n wt_n*near_n (float4, LDS) ; out = wT^T @ fused + b.
// Phase A: thread = (px4 = t&7, cg = t>>3), 8 channels each, float4 everywhere.
// Phase B: thread = (og = t&63, pg = t>>6): 4 out-ch x 8 px; LDS broadcast.
// ---------------------------------------------------------------------------
__global__ __launch_bounds__(256) void k_fuse(const float* __restrict__ feat,
                                              const float* __restrict__ nearf,
                                              const float* __restrict__ wt,
                                              const float* __restrict__ wT,
                                              const float* __restrict__ bf,
                                              float* __restrict__ out) {
    __shared__ float fl[Cc * LSTR];  // 40 KB -> 4 blocks/CU
    int blk = blockIdx.x;
    int b = blk / TPB;
    int tp = blk % TPB;
    int p0 = tp * TILE;
    int t = threadIdx.x;

    // ---- Phase A ----
    {
        int px4 = t & 7;
        int cg = t >> 3;
        int pp = p0 + px4 * 4;
        float4 w[4];
#pragma unroll
        for (int n = 0; n < 4; ++n)
            w[n] = *(const float4*)(wt + ((size_t)b * Nn + n) * HW + pp);
        const float* fb = feat + (size_t)b * Cc * HW + pp;
        const float* nb = nearf + (size_t)b * Nn * Cc * HW + pp;
#pragma unroll 2
        for (int k = 0; k < 8; ++k) {
            int c = cg * 8 + k;
            float4 v = *(const float4*)(fb + (size_t)c * HW);
#pragma unroll
            for (int n = 0; n < 4; ++n) {
                float4 u = *(const float4*)(nb + ((size_t)n * Cc + c) * HW);
                v.x += w[n].x * u.x; v.y += w[n].y * u.y;
                v.z += w[n].z * u.z; v.w += w[n].w * u.w;
            }
            *(float4*)(&fl[c * LSTR + px4 * 4]) = v;
        }
    }
    __syncthreads();

    // ---- Phase B ----
    {
        int og = t & 63;
        int pg = t >> 6;
        const float4* wT4 = (const float4*)wT;  // [Cc][Cc/4]
        float4 acc[4][2];
#pragma unroll
        for (int i = 0; i < 4; ++i) {
            float bi = bf[og * 4 + i];
            acc[i][0] = make_float4(bi, bi, bi, bi);
            acc[i][1] = make_float4(bi, bi, bi, bi);
        }
#pragma unroll 4
        for (int c = 0; c < Cc; ++c) {
            float4 wv = wT4[c * (Cc / 4) + og];
            float4 f0 = *(const float4*)(&fl[c * LSTR + pg * 8]);
            float4 f1 = *(const float4*)(&fl[c * LSTR + pg * 8 + 4]);
#pragma unroll
            for (int i = 0; i < 4; ++i) {
                float wi = (i == 0) ? wv.x : (i == 1) ? wv.y : (i == 2) ? wv.z : wv.w;
                acc[i][0].x += wi * f0.x; acc[i][0].y += wi * f0.y;
                acc[i][0].z += wi * f0.z; acc[i][0].w += wi * f0.w;
                acc[i][1].x += wi * f1.x; acc[i][1].y += wi * f1.y;
                acc[i][1].z += wi * f1.z; acc[i][1].w += wi * f1.w;
            }
        }
#pragma unroll
        for (int i = 0; i < 4; ++i) {
            float* ob = out + ((size_t)b * Cc + og * 4 + i) * HW + p0 + pg * 8;
            *(float4*)(ob + 0) = acc[i][0];
            *(float4*)(ob + 4) = acc[i][1];
        }
    }
}

extern "C" void kernel_launch(void* const* d_in, const int* in_sizes, int n_in,
                              void* d_out, int out_size, void* d_ws, size_t ws_size,
                              hipStream_t stream) {
    const float* feat = (const float*)d_in[0];   // [B,C,H,W]
    const float* nearf = (const float*)d_in[1];  // [B,N,C,H,W]
    const float* wf = (const float*)d_in[2];     // [C,C]
    const float* bf = (const float*)d_in[3];     // [C]
    float* out = (float*)d_out;                  // [B,C,H,W]

    char* ws = (char*)d_ws;
    float* thr = (float*)(ws + OFF_THR);
    float* wt = (float*)(ws + OFF_WT);
    float* wT = (float*)(ws + OFF_WTR);
    double* ps = (double*)(ws + OFF_SHR);
    unsigned* pcnt = (unsigned*)(ws + OFF_SHR);  // reuses ps region (dead by then)

    k_wtr<<<(Cc * Cc + 255) / 256, 256, 0, stream>>>(wf, wT);
    {
        dim3 grid((NMAP * NP4 + 255) / 256, SSPLIT);  // (297, 2)
        k_sums<<<grid, 256, 0, stream>>>(feat, nearf, ps);
    }
    k_thr<<<(NMAP * HW + 255) / 256, 256, 0, stream>>>(ps, thr);
    {
        dim3 grid((Bq * NP4 + 255) / 256, CSPLIT);    // (60, 16)
        k_census<<<grid, 256, 0, stream>>>(feat, nearf, thr, pcnt);
    }
    k_soft<<<(Bq * HW + 255) / 256, 256, 0, stream>>>(pcnt, wt);
    k_fuse<<<Bq * TPB, 256, 0, stream>>>(feat, nearf, wt, wT, bf, out);
}